// Round 1
// baseline (28.081 us; speedup 1.0000x reference)
//
#include <hip/hip_runtime.h>
#include <math.h>

namespace {

constexpr int KD   = 128;   // K * D floats per class row
constexpr int DH   = 32;    // half-dim
constexpr int Bn   = 512;   // batch
constexpr int Pn   = 2048;  // mc points
constexpr int PCHUNK = 256; // points per block
constexpr int NPART  = Bn * (Pn / PCHUNK); // 4096 partial sums
constexpr float MC_MULT_F = 4.0f / 2048.0f;
constexpr float EPS_F = 1e-9f;

__global__ __launch_bounds__(256) void mbel_main(
    const float* __restrict__ cw,   // (C, 128)
    const float* __restrict__ mc,   // (P, 32)
    const int*   __restrict__ nf1,  // (B, 2)
    float* __restrict__ partial)    // (NPART)
{
    __shared__ float s_cw[2 * KD];  // row_c then row_d
    __shared__ float s_red[4];

    const int tid = threadIdx.x;
    const int b   = blockIdx.y;

    const int idx0 = nf1[b * 2 + 0];
    const int idx1 = nf1[b * 2 + 1];
    {
        const float* src = (tid < KD) ? (cw + (size_t)idx0 * KD + tid)
                                      : (cw + (size_t)idx1 * KD + (tid - KD));
        s_cw[tid] = *src;
    }
    __syncthreads();

    const int p = blockIdx.x * PCHUNK + tid;

    // load this thread's MC point (32 floats, 8x float4, 128B-aligned)
    float pt[DH];
    const float4* mp = reinterpret_cast<const float4*>(mc + (size_t)p * DH);
    #pragma unroll
    for (int j = 0; j < DH / 4; ++j) {
        float4 v = mp[j];
        pt[4 * j + 0] = v.x; pt[4 * j + 1] = v.y;
        pt[4 * j + 2] = v.z; pt[4 * j + 3] = v.w;
    }

    // inc[e] = sigmoid( max_k min_d ( |off| - |p - cen| ) )
    float inc[2];
    #pragma unroll
    for (int e = 0; e < 2; ++e) {
        float mbest = -3.402823466e38f;
        #pragma unroll
        for (int k = 0; k < 2; ++k) {
            const float* box = s_cw + e * KD + k * 64;  // cen[0..31], off[32..63]
            float m = 3.402823466e38f;
            #pragma unroll
            for (int d = 0; d < DH; ++d) {
                float cen = box[d];           // LDS broadcast (uniform addr)
                float off = fabsf(box[DH + d]);
                float mg  = off - fabsf(pt[d] - cen);
                m = fminf(m, mg);
            }
            mbest = fmaxf(mbest, m);
        }
        inc[e] = 1.0f / (1.0f + expf(-mbest));
    }

    float area1 = fmaxf(inc[0] - 0.5f, 0.0f) * MC_MULT_F;
    float inter = fmaxf((inc[0] + inc[1]) * 0.5f - 0.5f, 0.0f) * MC_MULT_F;
    float term  = 1.0f - inter / (area1 + EPS_F);

    // deterministic block reduction: wave64 shfl tree, then 4 wave sums via LDS
    float v = term;
    #pragma unroll
    for (int off = 32; off > 0; off >>= 1) v += __shfl_down(v, off, 64);
    const int lane = tid & 63;
    const int wid  = tid >> 6;
    if (lane == 0) s_red[wid] = v;
    __syncthreads();
    if (tid == 0) {
        float t = s_red[0] + s_red[1] + s_red[2] + s_red[3];
        partial[blockIdx.y * gridDim.x + blockIdx.x] = t;
    }
}

__global__ __launch_bounds__(256) void mbel_final(
    const float* __restrict__ partial, float* __restrict__ out)
{
    __shared__ float s_red[4];
    float v = 0.0f;
    for (int i = threadIdx.x; i < NPART; i += 256) v += partial[i];
    #pragma unroll
    for (int off = 32; off > 0; off >>= 1) v += __shfl_down(v, off, 64);
    const int lane = threadIdx.x & 63;
    const int wid  = threadIdx.x >> 6;
    if (lane == 0) s_red[wid] = v;
    __syncthreads();
    if (threadIdx.x == 0) {
        float t = s_red[0] + s_red[1] + s_red[2] + s_red[3];
        float loss = t * (1.0f / ((float)Bn * (float)Pn));
        out[0] = fmaxf(loss, 0.0f);
    }
}

} // namespace

extern "C" void kernel_launch(void* const* d_in, const int* in_sizes, int n_in,
                              void* d_out, int out_size, void* d_ws, size_t ws_size,
                              hipStream_t stream) {
    const float* cw  = (const float*)d_in[0];  // class_weight (C, 128) f32
    const float* mc  = (const float*)d_in[1];  // mc_points (P, 32) f32
    const int*   nf1 = (const int*)d_in[2];    // nf1_data (B, 2) i32
    float* out = (float*)d_out;
    float* partial = (float*)d_ws;             // 4096 floats = 16 KB

    dim3 grid(Pn / PCHUNK, Bn);  // (8, 512)
    mbel_main<<<grid, 256, 0, stream>>>(cw, mc, nf1, partial);
    mbel_final<<<1, 256, 0, stream>>>(partial, out);
}